// Round 1
// baseline (3417.815 us; speedup 1.0000x reference)
//
#include <hip/hip_runtime.h>

// Problem constants (validated against in_sizes at launch)
#define H_DIM 128

// ---------------------------------------------------------------------------
// Scatter-add: for each edge e, out[dst[e]] += feat[src[e]] (float4 per thread,
// 32 threads per edge). Optionally accumulates degree count (transfer mean).
// ---------------------------------------------------------------------------
__global__ __launch_bounds__(256) void scatter_add_k(
    const float* __restrict__ feat, const int* __restrict__ src,
    const int* __restrict__ dst, float* __restrict__ out, int nE, int ostride,
    int ooff, float* __restrict__ cnt) {
  long tid = (long)blockIdx.x * blockDim.x + threadIdx.x;
  long total = (long)nE * 32;
  if (tid >= total) return;
  int e = (int)(tid >> 5);
  int c = ((int)tid & 31) * 4;
  int s = src[e];
  int d = dst[e];
  const float4 v = *(const float4*)(feat + (long)s * H_DIM + c);
  float* o = out + (long)d * ostride + ooff + c;
  atomicAdd(o + 0, v.x);
  atomicAdd(o + 1, v.y);
  atomicAdd(o + 2, v.z);
  atomicAdd(o + 3, v.w);
  if (cnt != nullptr && c == 0) atomicAdd(cnt + d, 1.0f);
}

// ---------------------------------------------------------------------------
// Router update: out = feat + relu(h[row, 0:256] @ W (256x128) + b)
// Block: 256 threads, 16 rows. Thread (g = tid>>7, j = tid&127) computes
// 8 rows (g*8..g*8+7) at column j. h staged in LDS (16KB), broadcast reads.
// ---------------------------------------------------------------------------
__global__ __launch_bounds__(256) void router_update_k(
    const float* __restrict__ h, const float* __restrict__ feat,
    const float* __restrict__ W, const float* __restrict__ b,
    float* __restrict__ out, int nrows) {
  __shared__ float hl[16][256];
  int tid = threadIdx.x;
  int row0 = blockIdx.x * 16;

  // stage 16 rows x 256 floats via float4 (1024 float4s, 4 per thread)
  for (int i = tid; i < 16 * 64; i += 256) {
    int r = i >> 6;
    int c4 = (i & 63) * 4;
    if (row0 + r < nrows)
      *(float4*)&hl[r][c4] = *(const float4*)&h[(long)(row0 + r) * 256 + c4];
  }
  __syncthreads();

  int j = tid & 127;
  int g = tid >> 7;
  float acc[8] = {0.f, 0.f, 0.f, 0.f, 0.f, 0.f, 0.f, 0.f};
  for (int k = 0; k < 256; k += 4) {
    float w0 = W[(k + 0) * 128 + j];
    float w1 = W[(k + 1) * 128 + j];
    float w2 = W[(k + 2) * 128 + j];
    float w3 = W[(k + 3) * 128 + j];
#pragma unroll
    for (int r = 0; r < 8; ++r) {
      float4 hv = *(const float4*)&hl[g * 8 + r][k];
      acc[r] = fmaf(hv.x, w0, acc[r]);
      acc[r] = fmaf(hv.y, w1, acc[r]);
      acc[r] = fmaf(hv.z, w2, acc[r]);
      acc[r] = fmaf(hv.w, w3, acc[r]);
    }
  }
  float bj = b[j];
#pragma unroll
  for (int r = 0; r < 8; ++r) {
    int row = row0 + g * 8 + r;
    if (row < nrows) {
      float v = acc[r] + bj;
      v = v > 0.f ? v : 0.f;
      out[(long)row * 128 + j] = feat[(long)row * 128 + j] + v;
    }
  }
}

// ---------------------------------------------------------------------------
// Packet update: h1 = s/max(cnt,1);  out = feat + relu(h1 @ W (128x128) + b)
// Same structure as router_update_k, K=128.
// ---------------------------------------------------------------------------
__global__ __launch_bounds__(256) void packet_update_k(
    const float* __restrict__ s, const float* __restrict__ cnt,
    const float* __restrict__ feat, const float* __restrict__ W,
    const float* __restrict__ b, float* __restrict__ out, int nrows) {
  __shared__ float hl[16][128];
  int tid = threadIdx.x;
  int row0 = blockIdx.x * 16;

  for (int i = tid; i < 16 * 32; i += 256) {
    int r = i >> 5;
    int c4 = (i & 31) * 4;
    if (row0 + r < nrows) {
      float c = cnt[row0 + r];
      float inv = 1.0f / (c > 1.0f ? c : 1.0f);
      float4 v = *(const float4*)&s[(long)(row0 + r) * 128 + c4];
      v.x *= inv;
      v.y *= inv;
      v.z *= inv;
      v.w *= inv;
      *(float4*)&hl[r][c4] = v;
    }
  }
  __syncthreads();

  int j = tid & 127;
  int g = tid >> 7;
  float acc[8] = {0.f, 0.f, 0.f, 0.f, 0.f, 0.f, 0.f, 0.f};
  for (int k = 0; k < 128; k += 4) {
    float w0 = W[(k + 0) * 128 + j];
    float w1 = W[(k + 1) * 128 + j];
    float w2 = W[(k + 2) * 128 + j];
    float w3 = W[(k + 3) * 128 + j];
#pragma unroll
    for (int r = 0; r < 8; ++r) {
      float4 hv = *(const float4*)&hl[g * 8 + r][k];
      acc[r] = fmaf(hv.x, w0, acc[r]);
      acc[r] = fmaf(hv.y, w1, acc[r]);
      acc[r] = fmaf(hv.z, w2, acc[r]);
      acc[r] = fmaf(hv.w, w3, acc[r]);
    }
  }
  float bj = b[j];
#pragma unroll
  for (int r = 0; r < 8; ++r) {
    int row = row0 + g * 8 + r;
    if (row < nrows) {
      float v = acc[r] + bj;
      v = v > 0.f ? v : 0.f;
      out[(long)row * 128 + j] = feat[(long)row * 128 + j] + v;
    }
  }
}

extern "C" void kernel_launch(void* const* d_in, const int* in_sizes, int n_in,
                              void* d_out, int out_size, void* d_ws,
                              size_t ws_size, hipStream_t stream) {
  const float* router_feat = (const float*)d_in[0];
  const float* packet_feat = (const float*)d_in[1];
  const float* W_r = (const float*)d_in[2];  // (256,128) row-major
  const float* b_r = (const float*)d_in[3];
  const float* W_p = (const float*)d_in[4];  // (128,128)
  const float* b_p = (const float*)d_in[5];
  const int* pass_src = (const int*)d_in[6];
  const int* pass_dst = (const int*)d_in[7];
  const int* connect_src = (const int*)d_in[8];
  const int* connect_dst = (const int*)d_in[9];
  const int* transfer_src = (const int*)d_in[10];
  const int* transfer_dst = (const int*)d_in[11];

  const int NRr = in_sizes[0] / H_DIM;  // 100000
  const int NPp = in_sizes[1] / H_DIM;  // 200000
  const int E_PASS = in_sizes[6];
  const int E_CONN = in_sizes[8];
  const int E_TRANS = in_sizes[10];

  float* out_r = (float*)d_out;
  float* out_p = out_r + (size_t)NRr * H_DIM;

  // workspace layout: h_r (NR x 256: h1|h2), s_p (NP x 128), cnt (NP)
  float* h_r = (float*)d_ws;
  float* s_p = h_r + (size_t)NRr * 256;
  float* cnt = s_p + (size_t)NPp * H_DIM;
  size_t ws_floats = (size_t)NRr * 256 + (size_t)NPp * H_DIM + (size_t)NPp;

  hipMemsetAsync(d_ws, 0, ws_floats * sizeof(float), stream);

  auto eblocks = [](int nE) { return (int)(((long)nE * 32 + 255) / 256); };

  // pass: router -> router, into h_r cols [0,128)
  scatter_add_k<<<eblocks(E_PASS), 256, 0, stream>>>(
      router_feat, pass_src, pass_dst, h_r, E_PASS, 256, 0, nullptr);
  // connect: packet -> router, into h_r cols [128,256)
  scatter_add_k<<<eblocks(E_CONN), 256, 0, stream>>>(
      packet_feat, connect_src, connect_dst, h_r, E_CONN, 256, 128, nullptr);
  // transfer: router -> packet, into s_p (+ degree count)
  scatter_add_k<<<eblocks(E_TRANS), 256, 0, stream>>>(
      router_feat, transfer_src, transfer_dst, s_p, E_TRANS, 128, 0, cnt);

  router_update_k<<<(NRr + 15) / 16, 256, 0, stream>>>(h_r, router_feat, W_r,
                                                       b_r, out_r, NRr);
  packet_update_k<<<(NPp + 15) / 16, 256, 0, stream>>>(s_p, cnt, packet_feat,
                                                       W_p, b_p, out_p, NPp);
}

// Round 2
// 659.034 us; speedup vs baseline: 5.1861x; 5.1861x over previous
//
#include <hip/hip_runtime.h>

#define H_DIM 128

// ===========================================================================
// CSR build: histogram -> multi-block exclusive scan -> permute
// ===========================================================================
__global__ __launch_bounds__(256) void hist_k(const int* __restrict__ dst,
                                              int* __restrict__ ro, int nE) {
  int e = blockIdx.x * blockDim.x + threadIdx.x;
  if (e < nE) atomicAdd(&ro[dst[e]], 1);
}

// Per-block (2048 elems) exclusive scan in-place; block sums -> bsums.
__global__ __launch_bounds__(256) void scan1_k(int* __restrict__ a, int n,
                                               int* __restrict__ bsums) {
  __shared__ int ts[256];
  int t = threadIdx.x;
  int base = blockIdx.x * 2048 + t * 8;
  int v[8];
  int s = 0;
#pragma unroll
  for (int k = 0; k < 8; ++k) {
    v[k] = (base + k < n) ? a[base + k] : 0;
    s += v[k];
  }
  ts[t] = s;
  __syncthreads();
  for (int off = 1; off < 256; off <<= 1) {
    int x = (t >= off) ? ts[t - off] : 0;
    __syncthreads();
    ts[t] += x;
    __syncthreads();
  }
  if (t == 0) bsums[blockIdx.x] = ts[255];
  int run = (t == 0) ? 0 : ts[t - 1];
#pragma unroll
  for (int k = 0; k < 8; ++k) {
    int x = v[k];
    if (base + k < n) a[base + k] = run;
    run += x;
  }
}

// Single-block exclusive scan of bsums (nb <= 256).
__global__ __launch_bounds__(256) void scan2_k(int* __restrict__ bsums,
                                               int nb) {
  __shared__ int ts[256];
  int t = threadIdx.x;
  int v = (t < nb) ? bsums[t] : 0;
  ts[t] = v;
  __syncthreads();
  for (int off = 1; off < 256; off <<= 1) {
    int x = (t >= off) ? ts[t - off] : 0;
    __syncthreads();
    ts[t] += x;
    __syncthreads();
  }
  int excl = (t == 0) ? 0 : ts[t - 1];
  if (t < nb) bsums[t] = excl;
}

// Add block offsets; copy to cursor; write sentinel ro[n] = total.
__global__ __launch_bounds__(256) void scan3_k(int* __restrict__ a, int n,
                                               const int* __restrict__ bsums,
                                               int* __restrict__ cur,
                                               int total) {
  int i = blockIdx.x * blockDim.x + threadIdx.x;
  if (i < n) {
    int v = a[i] + bsums[i / 2048];
    a[i] = v;
    cur[i] = v;
  }
  if (i == 0) a[n] = total;
}

__global__ __launch_bounds__(256) void permute_k(const int* __restrict__ src,
                                                 const int* __restrict__ dst,
                                                 int* __restrict__ cur,
                                                 int* __restrict__ es, int nE) {
  int e = blockIdx.x * blockDim.x + threadIdx.x;
  if (e < nE) {
    int d = dst[e];
    int p = atomicAdd(&cur[d], 1);
    es[p] = src[e];
  }
}

// ===========================================================================
// Fused router: gather(pass from router_feat) + gather(connect from
// packet_feat) into LDS [16][256], then GEMM(256x128)+ReLU+residual.
// Block = 256 threads (4 waves), 16 rows. Gather: 1 wave per row, lane
// handles cols {lane, lane+64}; 2-edge unroll for MLP.
// ===========================================================================
__global__ __launch_bounds__(256) void router_fused_k(
    const float* __restrict__ rf, const float* __restrict__ pf,
    const int* __restrict__ ro_pass, const int* __restrict__ es_pass,
    const int* __restrict__ ro_conn, const int* __restrict__ es_conn,
    const float* __restrict__ W, const float* __restrict__ b,
    float* __restrict__ out, int nrows) {
  __shared__ float hl[16][256];
  int tid = threadIdx.x;
  int lane = tid & 63;
  int wv = tid >> 6;
  int row0 = blockIdx.x * 16;

#pragma unroll
  for (int rr = 0; rr < 4; ++rr) {
    int r = wv * 4 + rr;
    int row = row0 + r;
    if (row < nrows) {
      {  // pass: router -> router
        int s0 = ro_pass[row], e1 = ro_pass[row + 1];
        float a0 = 0.f, a1 = 0.f, c0 = 0.f, c1 = 0.f;
        int e = s0;
        for (; e + 1 < e1; e += 2) {
          long s1 = (long)es_pass[e] * H_DIM;
          long s2 = (long)es_pass[e + 1] * H_DIM;
          a0 += rf[s1 + lane];
          a1 += rf[s1 + 64 + lane];
          c0 += rf[s2 + lane];
          c1 += rf[s2 + 64 + lane];
        }
        if (e < e1) {
          long s1 = (long)es_pass[e] * H_DIM;
          a0 += rf[s1 + lane];
          a1 += rf[s1 + 64 + lane];
        }
        hl[r][lane] = a0 + c0;
        hl[r][64 + lane] = a1 + c1;
      }
      {  // connect: packet -> router
        int s0 = ro_conn[row], e1 = ro_conn[row + 1];
        float a0 = 0.f, a1 = 0.f, c0 = 0.f, c1 = 0.f;
        int e = s0;
        for (; e + 1 < e1; e += 2) {
          long s1 = (long)es_conn[e] * H_DIM;
          long s2 = (long)es_conn[e + 1] * H_DIM;
          a0 += pf[s1 + lane];
          a1 += pf[s1 + 64 + lane];
          c0 += pf[s2 + lane];
          c1 += pf[s2 + 64 + lane];
        }
        if (e < e1) {
          long s1 = (long)es_conn[e] * H_DIM;
          a0 += pf[s1 + lane];
          a1 += pf[s1 + 64 + lane];
        }
        hl[r][128 + lane] = a0 + c0;
        hl[r][192 + lane] = a1 + c1;
      }
    }
  }
  __syncthreads();

  int j = tid & 127;
  int g = tid >> 7;
  float acc[8] = {0.f, 0.f, 0.f, 0.f, 0.f, 0.f, 0.f, 0.f};
  for (int k = 0; k < 256; k += 4) {
    float w0 = W[(k + 0) * 128 + j];
    float w1 = W[(k + 1) * 128 + j];
    float w2 = W[(k + 2) * 128 + j];
    float w3 = W[(k + 3) * 128 + j];
#pragma unroll
    for (int r = 0; r < 8; ++r) {
      float4 hv = *(const float4*)&hl[g * 8 + r][k];
      acc[r] = fmaf(hv.x, w0, acc[r]);
      acc[r] = fmaf(hv.y, w1, acc[r]);
      acc[r] = fmaf(hv.z, w2, acc[r]);
      acc[r] = fmaf(hv.w, w3, acc[r]);
    }
  }
  float bj = b[j];
#pragma unroll
  for (int r = 0; r < 8; ++r) {
    int row = row0 + g * 8 + r;
    if (row < nrows) {
      float v = acc[r] + bj;
      v = v > 0.f ? v : 0.f;
      out[(long)row * H_DIM + j] = rf[(long)row * H_DIM + j] + v;
    }
  }
}

// ===========================================================================
// Fused packet: gather(transfer from router_feat), mean via CSR degree,
// then GEMM(128x128)+ReLU+residual.
// ===========================================================================
__global__ __launch_bounds__(256) void packet_fused_k(
    const float* __restrict__ rf, const float* __restrict__ pf,
    const int* __restrict__ ro, const int* __restrict__ es,
    const float* __restrict__ W, const float* __restrict__ b,
    float* __restrict__ out, int nrows) {
  __shared__ float hl[16][128];
  int tid = threadIdx.x;
  int lane = tid & 63;
  int wv = tid >> 6;
  int row0 = blockIdx.x * 16;

#pragma unroll
  for (int rr = 0; rr < 4; ++rr) {
    int r = wv * 4 + rr;
    int row = row0 + r;
    if (row < nrows) {
      int s0 = ro[row], e1 = ro[row + 1];
      float a0 = 0.f, a1 = 0.f, c0 = 0.f, c1 = 0.f;
      int e = s0;
      for (; e + 1 < e1; e += 2) {
        long s1 = (long)es[e] * H_DIM;
        long s2 = (long)es[e + 1] * H_DIM;
        a0 += rf[s1 + lane];
        a1 += rf[s1 + 64 + lane];
        c0 += rf[s2 + lane];
        c1 += rf[s2 + 64 + lane];
      }
      if (e < e1) {
        long s1 = (long)es[e] * H_DIM;
        a0 += rf[s1 + lane];
        a1 += rf[s1 + 64 + lane];
      }
      int deg = e1 - s0;
      float inv = 1.0f / (float)(deg > 1 ? deg : 1);
      hl[r][lane] = (a0 + c0) * inv;
      hl[r][64 + lane] = (a1 + c1) * inv;
    }
  }
  __syncthreads();

  int j = tid & 127;
  int g = tid >> 7;
  float acc[8] = {0.f, 0.f, 0.f, 0.f, 0.f, 0.f, 0.f, 0.f};
  for (int k = 0; k < 128; k += 4) {
    float w0 = W[(k + 0) * 128 + j];
    float w1 = W[(k + 1) * 128 + j];
    float w2 = W[(k + 2) * 128 + j];
    float w3 = W[(k + 3) * 128 + j];
#pragma unroll
    for (int r = 0; r < 8; ++r) {
      float4 hv = *(const float4*)&hl[g * 8 + r][k];
      acc[r] = fmaf(hv.x, w0, acc[r]);
      acc[r] = fmaf(hv.y, w1, acc[r]);
      acc[r] = fmaf(hv.z, w2, acc[r]);
      acc[r] = fmaf(hv.w, w3, acc[r]);
    }
  }
  float bj = b[j];
#pragma unroll
  for (int r = 0; r < 8; ++r) {
    int row = row0 + g * 8 + r;
    if (row < nrows) {
      float v = acc[r] + bj;
      v = v > 0.f ? v : 0.f;
      out[(long)row * H_DIM + j] = pf[(long)row * H_DIM + j] + v;
    }
  }
}

extern "C" void kernel_launch(void* const* d_in, const int* in_sizes, int n_in,
                              void* d_out, int out_size, void* d_ws,
                              size_t ws_size, hipStream_t stream) {
  const float* router_feat = (const float*)d_in[0];
  const float* packet_feat = (const float*)d_in[1];
  const float* W_r = (const float*)d_in[2];
  const float* b_r = (const float*)d_in[3];
  const float* W_p = (const float*)d_in[4];
  const float* b_p = (const float*)d_in[5];
  const int* pass_src = (const int*)d_in[6];
  const int* pass_dst = (const int*)d_in[7];
  const int* connect_src = (const int*)d_in[8];
  const int* connect_dst = (const int*)d_in[9];
  const int* transfer_src = (const int*)d_in[10];
  const int* transfer_dst = (const int*)d_in[11];

  const int NRr = in_sizes[0] / H_DIM;  // 100000
  const int NPp = in_sizes[1] / H_DIM;  // 200000
  const int E_PASS = in_sizes[6];
  const int E_CONN = in_sizes[8];
  const int E_TRANS = in_sizes[10];

  float* out_r = (float*)d_out;
  float* out_p = out_r + (size_t)NRr * H_DIM;

  // workspace (ints): ro_pass|ro_conn|ro_trans (contiguous, zeroed together),
  // cursors, sorted-src arrays, scan block-sums scratch.
  int* ro_pass = (int*)d_ws;
  int* ro_conn = ro_pass + (NRr + 1);
  int* ro_trans = ro_conn + (NRr + 1);
  int* cur_pass = ro_trans + (NPp + 1);
  int* cur_conn = cur_pass + NRr;
  int* cur_trans = cur_conn + NRr;
  int* es_pass = cur_trans + NPp;
  int* es_conn = es_pass + E_PASS;
  int* es_trans = es_conn + E_CONN;
  int* bsums = es_trans + E_TRANS;  // <=256 entries, reused sequentially

  size_t ro_bytes = (size_t)((NRr + 1) + (NRr + 1) + (NPp + 1)) * sizeof(int);
  hipMemsetAsync(d_ws, 0, ro_bytes, stream);

  auto build_csr = [&](const int* src, const int* dst, int* ro, int* cur,
                       int* es, int n_nodes, int nE) {
    int egrid = (nE + 255) / 256;
    hist_k<<<egrid, 256, 0, stream>>>(dst, ro, nE);
    int nb = (n_nodes + 2047) / 2048;
    scan1_k<<<nb, 256, 0, stream>>>(ro, n_nodes, bsums);
    scan2_k<<<1, 256, 0, stream>>>(bsums, nb);
    scan3_k<<<(n_nodes + 255) / 256, 256, 0, stream>>>(ro, n_nodes, bsums, cur,
                                                       nE);
    permute_k<<<egrid, 256, 0, stream>>>(src, dst, cur, es, nE);
  };

  build_csr(pass_src, pass_dst, ro_pass, cur_pass, es_pass, NRr, E_PASS);
  build_csr(connect_src, connect_dst, ro_conn, cur_conn, es_conn, NRr, E_CONN);
  build_csr(transfer_src, transfer_dst, ro_trans, cur_trans, es_trans, NPp,
            E_TRANS);

  router_fused_k<<<(NRr + 15) / 16, 256, 0, stream>>>(
      router_feat, packet_feat, ro_pass, es_pass, ro_conn, es_conn, W_r, b_r,
      out_r, NRr);
  packet_fused_k<<<(NPp + 15) / 16, 256, 0, stream>>>(
      router_feat, packet_feat, ro_trans, es_trans, W_p, b_p, out_p, NPp);
}

// Round 3
// 584.351 us; speedup vs baseline: 5.8489x; 1.1278x over previous
//
#include <hip/hip_runtime.h>

#define H_DIM 128

// ===========================================================================
// CSR build: histogram -> multi-block exclusive scan -> permute
// ===========================================================================
__global__ __launch_bounds__(256) void hist_k(const int* __restrict__ dst,
                                              int* __restrict__ ro, int nE) {
  int e = blockIdx.x * blockDim.x + threadIdx.x;
  if (e < nE) atomicAdd(&ro[dst[e]], 1);
}

// Per-block (2048 elems) exclusive scan in-place; block sums -> bsums.
__global__ __launch_bounds__(256) void scan1_k(int* __restrict__ a, int n,
                                               int* __restrict__ bsums) {
  __shared__ int ts[256];
  int t = threadIdx.x;
  int base = blockIdx.x * 2048 + t * 8;
  int v[8];
  int s = 0;
#pragma unroll
  for (int k = 0; k < 8; ++k) {
    v[k] = (base + k < n) ? a[base + k] : 0;
    s += v[k];
  }
  ts[t] = s;
  __syncthreads();
  for (int off = 1; off < 256; off <<= 1) {
    int x = (t >= off) ? ts[t - off] : 0;
    __syncthreads();
    ts[t] += x;
    __syncthreads();
  }
  if (t == 0) bsums[blockIdx.x] = ts[255];
  int run = (t == 0) ? 0 : ts[t - 1];
#pragma unroll
  for (int k = 0; k < 8; ++k) {
    int x = v[k];
    if (base + k < n) a[base + k] = run;
    run += x;
  }
}

// Single-block exclusive scan of bsums (nb <= 256).
__global__ __launch_bounds__(256) void scan2_k(int* __restrict__ bsums,
                                               int nb) {
  __shared__ int ts[256];
  int t = threadIdx.x;
  int v = (t < nb) ? bsums[t] : 0;
  ts[t] = v;
  __syncthreads();
  for (int off = 1; off < 256; off <<= 1) {
    int x = (t >= off) ? ts[t - off] : 0;
    __syncthreads();
    ts[t] += x;
    __syncthreads();
  }
  int excl = (t == 0) ? 0 : ts[t - 1];
  if (t < nb) bsums[t] = excl;
}

// Add block offsets; copy to cursor; write sentinel ro[n] = total.
__global__ __launch_bounds__(256) void scan3_k(int* __restrict__ a, int n,
                                               const int* __restrict__ bsums,
                                               int* __restrict__ cur,
                                               int total) {
  int i = blockIdx.x * blockDim.x + threadIdx.x;
  if (i < n) {
    int v = a[i] + bsums[i / 2048];
    a[i] = v;
    cur[i] = v;
  }
  if (i == 0) a[n] = total;
}

__global__ __launch_bounds__(256) void permute_k(const int* __restrict__ src,
                                                 const int* __restrict__ dst,
                                                 int* __restrict__ cur,
                                                 int* __restrict__ es, int nE) {
  int e = blockIdx.x * blockDim.x + threadIdx.x;
  if (e < nE) {
    int d = dst[e];
    int p = atomicAdd(&cur[d], 1);
    es[p] = src[e];
  }
}

// ---------------------------------------------------------------------------
// Gather one row-segment (128 floats across a 32-lane group as float4),
// 4-edge unroll -> 4 outstanding loads per lane.
// ---------------------------------------------------------------------------
__device__ __forceinline__ float4 gather_row(const float* __restrict__ tbl,
                                             const int* __restrict__ es,
                                             int s0, int e1, int c4) {
  float4 a0 = {0.f, 0.f, 0.f, 0.f}, a1 = a0, a2 = a0, a3 = a0;
  int e = s0;
  for (; e + 3 < e1; e += 4) {
    int i0 = es[e], i1 = es[e + 1], i2 = es[e + 2], i3 = es[e + 3];
    float4 v0 = *(const float4*)(tbl + (long)i0 * H_DIM + c4);
    float4 v1 = *(const float4*)(tbl + (long)i1 * H_DIM + c4);
    float4 v2 = *(const float4*)(tbl + (long)i2 * H_DIM + c4);
    float4 v3 = *(const float4*)(tbl + (long)i3 * H_DIM + c4);
    a0.x += v0.x; a0.y += v0.y; a0.z += v0.z; a0.w += v0.w;
    a1.x += v1.x; a1.y += v1.y; a1.z += v1.z; a1.w += v1.w;
    a2.x += v2.x; a2.y += v2.y; a2.z += v2.z; a2.w += v2.w;
    a3.x += v3.x; a3.y += v3.y; a3.z += v3.z; a3.w += v3.w;
  }
  for (; e < e1; ++e) {
    int i0 = es[e];
    float4 v0 = *(const float4*)(tbl + (long)i0 * H_DIM + c4);
    a0.x += v0.x; a0.y += v0.y; a0.z += v0.z; a0.w += v0.w;
  }
  float4 s;
  s.x = (a0.x + a1.x) + (a2.x + a3.x);
  s.y = (a0.y + a1.y) + (a2.y + a3.y);
  s.z = (a0.z + a1.z) + (a2.z + a3.z);
  s.w = (a0.w + a1.w) + (a2.w + a3.w);
  return s;
}

// ===========================================================================
// Single fused kernel. Blocks [0, nrb): router rows; [nrb, nrb+npb): packet.
// Per block: 16 rows. Gather phase: each wave handles 2 rows at a time
// (subrow = lane>>5, c4 = (lane&31)*4), float4 loads. GEMM phase: thread
// (g=tid>>7, j=tid&127) computes 8 rows x 1 col from LDS + streamed W.
// ===========================================================================
__global__ __launch_bounds__(256) void fused_k(
    const float* __restrict__ rf, const float* __restrict__ pf,
    const int* __restrict__ ro_pass, const int* __restrict__ es_pass,
    const int* __restrict__ ro_conn, const int* __restrict__ es_conn,
    const int* __restrict__ ro_trans, const int* __restrict__ es_trans,
    const float* __restrict__ W_r, const float* __restrict__ b_r,
    const float* __restrict__ W_p, const float* __restrict__ b_p,
    float* __restrict__ out_r, float* __restrict__ out_p, int nrb, int NRn,
    int NPn) {
  __shared__ float hl[16][256];
  int tid = threadIdx.x;
  int lane = tid & 63;
  int wv = tid >> 6;
  int sub = lane >> 5;
  int c4 = (lane & 31) * 4;
  bool is_router = (int)blockIdx.x < nrb;

  if (is_router) {
    int row0 = blockIdx.x * 16;
#pragma unroll
    for (int p = 0; p < 2; ++p) {
      int r = wv * 4 + p * 2 + sub;
      int row = row0 + r;
      if (row < NRn) {
        int s0 = ro_pass[row], e1 = ro_pass[row + 1];
        *(float4*)&hl[r][c4] = gather_row(rf, es_pass, s0, e1, c4);
        s0 = ro_conn[row];
        e1 = ro_conn[row + 1];
        *(float4*)&hl[r][128 + c4] = gather_row(pf, es_conn, s0, e1, c4);
      }
    }
    __syncthreads();

    int j = tid & 127;
    int g = tid >> 7;
    float acc[8] = {0.f, 0.f, 0.f, 0.f, 0.f, 0.f, 0.f, 0.f};
    for (int k = 0; k < 256; k += 4) {
      float w0 = W_r[(k + 0) * 128 + j];
      float w1 = W_r[(k + 1) * 128 + j];
      float w2 = W_r[(k + 2) * 128 + j];
      float w3 = W_r[(k + 3) * 128 + j];
#pragma unroll
      for (int r = 0; r < 8; ++r) {
        float4 hv = *(const float4*)&hl[g * 8 + r][k];
        acc[r] = fmaf(hv.x, w0, acc[r]);
        acc[r] = fmaf(hv.y, w1, acc[r]);
        acc[r] = fmaf(hv.z, w2, acc[r]);
        acc[r] = fmaf(hv.w, w3, acc[r]);
      }
    }
    float bj = b_r[j];
#pragma unroll
    for (int r = 0; r < 8; ++r) {
      int row = row0 + g * 8 + r;
      if (row < NRn) {
        float v = acc[r] + bj;
        v = v > 0.f ? v : 0.f;
        out_r[(long)row * H_DIM + j] = rf[(long)row * H_DIM + j] + v;
      }
    }
  } else {
    int row0 = (blockIdx.x - nrb) * 16;
#pragma unroll
    for (int p = 0; p < 2; ++p) {
      int r = wv * 4 + p * 2 + sub;
      int row = row0 + r;
      if (row < NPn) {
        int s0 = ro_trans[row], e1 = ro_trans[row + 1];
        float4 s = gather_row(rf, es_trans, s0, e1, c4);
        int deg = e1 - s0;
        float inv = 1.0f / (float)(deg > 1 ? deg : 1);
        s.x *= inv;
        s.y *= inv;
        s.z *= inv;
        s.w *= inv;
        *(float4*)&hl[r][c4] = s;
      }
    }
    __syncthreads();

    int j = tid & 127;
    int g = tid >> 7;
    float acc[8] = {0.f, 0.f, 0.f, 0.f, 0.f, 0.f, 0.f, 0.f};
    for (int k = 0; k < 128; k += 4) {
      float w0 = W_p[(k + 0) * 128 + j];
      float w1 = W_p[(k + 1) * 128 + j];
      float w2 = W_p[(k + 2) * 128 + j];
      float w3 = W_p[(k + 3) * 128 + j];
#pragma unroll
      for (int r = 0; r < 8; ++r) {
        float4 hv = *(const float4*)&hl[g * 8 + r][k];
        acc[r] = fmaf(hv.x, w0, acc[r]);
        acc[r] = fmaf(hv.y, w1, acc[r]);
        acc[r] = fmaf(hv.z, w2, acc[r]);
        acc[r] = fmaf(hv.w, w3, acc[r]);
      }
    }
    float bj = b_p[j];
#pragma unroll
    for (int r = 0; r < 8; ++r) {
      int row = row0 + g * 8 + r;
      if (row < NPn) {
        float v = acc[r] + bj;
        v = v > 0.f ? v : 0.f;
        out_p[(long)row * H_DIM + j] = pf[(long)row * H_DIM + j] + v;
      }
    }
  }
}

extern "C" void kernel_launch(void* const* d_in, const int* in_sizes, int n_in,
                              void* d_out, int out_size, void* d_ws,
                              size_t ws_size, hipStream_t stream) {
  const float* router_feat = (const float*)d_in[0];
  const float* packet_feat = (const float*)d_in[1];
  const float* W_r = (const float*)d_in[2];
  const float* b_r = (const float*)d_in[3];
  const float* W_p = (const float*)d_in[4];
  const float* b_p = (const float*)d_in[5];
  const int* pass_src = (const int*)d_in[6];
  const int* pass_dst = (const int*)d_in[7];
  const int* connect_src = (const int*)d_in[8];
  const int* connect_dst = (const int*)d_in[9];
  const int* transfer_src = (const int*)d_in[10];
  const int* transfer_dst = (const int*)d_in[11];

  const int NRr = in_sizes[0] / H_DIM;  // 100000
  const int NPp = in_sizes[1] / H_DIM;  // 200000
  const int E_PASS = in_sizes[6];
  const int E_CONN = in_sizes[8];
  const int E_TRANS = in_sizes[10];

  float* out_r = (float*)d_out;
  float* out_p = out_r + (size_t)NRr * H_DIM;

  // workspace (ints)
  int* ro_pass = (int*)d_ws;
  int* ro_conn = ro_pass + (NRr + 1);
  int* ro_trans = ro_conn + (NRr + 1);
  int* cur_pass = ro_trans + (NPp + 1);
  int* cur_conn = cur_pass + NRr;
  int* cur_trans = cur_conn + NRr;
  int* es_pass = cur_trans + NPp;
  int* es_conn = es_pass + E_PASS;
  int* es_trans = es_conn + E_CONN;
  int* bsums = es_trans + E_TRANS;  // <=256 entries, reused sequentially

  size_t ro_bytes = (size_t)((NRr + 1) + (NRr + 1) + (NPp + 1)) * sizeof(int);
  hipMemsetAsync(d_ws, 0, ro_bytes, stream);

  auto build_csr = [&](const int* src, const int* dst, int* ro, int* cur,
                       int* es, int n_nodes, int nE) {
    int egrid = (nE + 255) / 256;
    hist_k<<<egrid, 256, 0, stream>>>(dst, ro, nE);
    int nb = (n_nodes + 2047) / 2048;
    scan1_k<<<nb, 256, 0, stream>>>(ro, n_nodes, bsums);
    scan2_k<<<1, 256, 0, stream>>>(bsums, nb);
    scan3_k<<<(n_nodes + 255) / 256, 256, 0, stream>>>(ro, n_nodes, bsums, cur,
                                                       nE);
    permute_k<<<egrid, 256, 0, stream>>>(src, dst, cur, es, nE);
  };

  build_csr(pass_src, pass_dst, ro_pass, cur_pass, es_pass, NRr, E_PASS);
  build_csr(connect_src, connect_dst, ro_conn, cur_conn, es_conn, NRr, E_CONN);
  build_csr(transfer_src, transfer_dst, ro_trans, cur_trans, es_trans, NPp,
            E_TRANS);

  int nrb = (NRr + 15) / 16;
  int npb = (NPp + 15) / 16;
  fused_k<<<nrb + npb, 256, 0, stream>>>(
      router_feat, packet_feat, ro_pass, es_pass, ro_conn, es_conn, ro_trans,
      es_trans, W_r, b_r, W_p, b_p, out_r, out_p, nrb, NRr, NPp);
}

// Round 4
// 440.078 us; speedup vs baseline: 7.7664x; 1.3278x over previous
//
#include <hip/hip_runtime.h>

#define H_DIM 128

typedef __attribute__((ext_vector_type(8))) short short8v;
typedef __attribute__((ext_vector_type(4))) float f32x4;

__device__ __forceinline__ ushort f2bf(float f) {
  unsigned u = __builtin_bit_cast(unsigned, f);
  u += 0x7fffu + ((u >> 16) & 1u);  // RNE
  return (ushort)(u >> 16);
}
__device__ __forceinline__ float bflo(unsigned u) {
  return __builtin_bit_cast(float, u << 16);
}
__device__ __forceinline__ float bfhi(unsigned u) {
  return __builtin_bit_cast(float, u & 0xffff0000u);
}

// ===========================================================================
// CSR build (concatenated): ro = [pass(NR) | connect(NR) | transfer(NP)] + 1
// sentinel. One global scan gives offsets into ONE contiguous es array.
// ===========================================================================
__global__ __launch_bounds__(256) void hist_all_k(
    const int* __restrict__ d0, const int* __restrict__ d1,
    const int* __restrict__ d2, int* __restrict__ ro, int n0, int n1, int n2,
    int NRn) {
  int e = blockIdx.x * blockDim.x + threadIdx.x;
  if (e < n0)
    atomicAdd(&ro[d0[e]], 1);
  else if (e < n0 + n1)
    atomicAdd(&ro[NRn + d1[e - n0]], 1);
  else if (e < n0 + n1 + n2)
    atomicAdd(&ro[2 * NRn + d2[e - n0 - n1]], 1);
}

__global__ __launch_bounds__(256) void scan1_k(int* __restrict__ a, int n,
                                               int* __restrict__ bsums) {
  __shared__ int ts[256];
  int t = threadIdx.x;
  int base = blockIdx.x * 2048 + t * 8;
  int v[8];
  int s = 0;
#pragma unroll
  for (int k = 0; k < 8; ++k) {
    v[k] = (base + k < n) ? a[base + k] : 0;
    s += v[k];
  }
  ts[t] = s;
  __syncthreads();
  for (int off = 1; off < 256; off <<= 1) {
    int x = (t >= off) ? ts[t - off] : 0;
    __syncthreads();
    ts[t] += x;
    __syncthreads();
  }
  if (t == 0) bsums[blockIdx.x] = ts[255];
  int run = (t == 0) ? 0 : ts[t - 1];
#pragma unroll
  for (int k = 0; k < 8; ++k) {
    int x = v[k];
    if (base + k < n) a[base + k] = run;
    run += x;
  }
}

__global__ __launch_bounds__(256) void scan2_k(int* __restrict__ bsums,
                                               int nb) {
  __shared__ int ts[256];
  int t = threadIdx.x;
  int v = (t < nb) ? bsums[t] : 0;
  ts[t] = v;
  __syncthreads();
  for (int off = 1; off < 256; off <<= 1) {
    int x = (t >= off) ? ts[t - off] : 0;
    __syncthreads();
    ts[t] += x;
    __syncthreads();
  }
  int excl = (t == 0) ? 0 : ts[t - 1];
  if (t < nb) bsums[t] = excl;
}

__global__ __launch_bounds__(256) void scan3_k(int* __restrict__ a, int n,
                                               const int* __restrict__ bsums,
                                               int* __restrict__ cur,
                                               int total) {
  int i = blockIdx.x * blockDim.x + threadIdx.x;
  if (i < n) {
    int v = a[i] + bsums[i / 2048];
    a[i] = v;
    cur[i] = v;
  }
  if (i == 0) a[n] = total;
}

__global__ __launch_bounds__(256) void permute_all_k(
    const int* __restrict__ s0a, const int* __restrict__ d0a,
    const int* __restrict__ s1a, const int* __restrict__ d1a,
    const int* __restrict__ s2a, const int* __restrict__ d2a,
    int* __restrict__ cur, int* __restrict__ es, int n0, int n1, int n2,
    int NRn) {
  int e = blockIdx.x * blockDim.x + threadIdx.x;
  int src, slot;
  if (e < n0) {
    slot = d0a[e];
    src = s0a[e];
  } else if (e < n0 + n1) {
    int i = e - n0;
    slot = NRn + d1a[i];
    src = s1a[i];
  } else if (e < n0 + n1 + n2) {
    int i = e - n0 - n1;
    slot = 2 * NRn + d2a[i];
    src = s2a[i];
  } else
    return;
  int p = atomicAdd(&cur[slot], 1);
  es[p] = src;
}

// ===========================================================================
// Cast + transpose weights to bf16: Wt = [3][128][128], Wt[m][j][k] = W[k][j]
// m=0: W_r[0:128], m=1: W_r[128:256], m=2: W_p
// ===========================================================================
__global__ __launch_bounds__(256) void castw_k(const float* __restrict__ W_r,
                                               const float* __restrict__ W_p,
                                               ushort* __restrict__ Wt) {
  int i = blockIdx.x * blockDim.x + threadIdx.x;
  if (i >= 3 * 128 * 128) return;
  int m = i >> 14;
  int j = (i >> 7) & 127;
  int k = i & 127;
  float v = (m == 0)   ? W_r[k * 128 + j]
            : (m == 1) ? W_r[(128 + k) * 128 + j]
                       : W_p[k * 128 + j];
  Wt[i] = f2bf(v);
}

// ===========================================================================
// Dense GEMM  Y(bf16) = X(f32, Mx128) @ W(128x128)  via MFMA 16x16x32 bf16.
// One kernel, 3 segments (Y1=rf@W1, Y2=pf@W2, Yp=rf@Wp) by blockIdx.
// Block: 256 thr = 4 waves, 64 rows. Wt staged in LDS (XOR-swizzled, k8
// granularity) -> conflict-free ds_read_b128 B-frags. A-frags loaded
// directly from global fp32 (2x dwordx4/lane) and converted inline.
// Epilogue: D -> LDS (reusing Wt space) -> packed bf16 stores.
// ===========================================================================
__global__ __launch_bounds__(256) void gemm_k(
    const float* __restrict__ rf, const float* __restrict__ pf,
    const ushort* __restrict__ Wt, ushort* __restrict__ Y1,
    ushort* __restrict__ Y2, ushort* __restrict__ Yp, int nb1, int nb2, int M1,
    int M2) {
  __shared__ float lds_f[8192];  // 32KB: Wt(bf16) during K-loop, D(f32) after
  ushort* wl = (ushort*)lds_f;

  int bid = blockIdx.x;
  const float* X;
  ushort* Y;
  const ushort* Wg;
  int M, row0;
  if (bid < nb1) {
    X = rf; Y = Y1; Wg = Wt; M = M1; row0 = bid * 64;
  } else if (bid < nb1 + nb2) {
    X = pf; Y = Y2; Wg = Wt + 16384; M = M2; row0 = (bid - nb1) * 64;
  } else {
    X = rf; Y = Yp; Wg = Wt + 32768; M = M1; row0 = (bid - nb1 - nb2) * 64;
  }

  int tid = threadIdx.x;
  // stage Wt -> LDS, 16B chunks, XOR swizzle on 8-ushort granularity
  {
    const uint4* src = (const uint4*)Wg;
    for (int i = tid; i < 2048; i += 256) {
      int j = i >> 4;
      int k8 = (i & 15) * 8;
      int kk = k8 ^ ((j & 7) << 3);
      *(uint4*)&wl[j * 128 + kk] = src[i];
    }
  }
  __syncthreads();

  int lane = tid & 63;
  int wv = tid >> 6;
  int l15 = lane & 15;
  int kq = lane >> 4;  // k-chunk of 8
  int rowl = wv * 16 + l15;
  int grow = row0 + rowl;
  int growc = grow < M ? grow : M - 1;

  f32x4 acc[8];
#pragma unroll
  for (int t = 0; t < 8; ++t) {
    f32x4 z = {0.f, 0.f, 0.f, 0.f};
    acc[t] = z;
  }

#pragma unroll
  for (int ks = 0; ks < 4; ++ks) {
    int k0 = ks * 32;
    const float* ap = X + (long)growc * H_DIM + k0 + kq * 8;
    float4 a0 = *(const float4*)ap;
    float4 a1 = *(const float4*)(ap + 4);
    short8v af;
    af[0] = (short)f2bf(a0.x);
    af[1] = (short)f2bf(a0.y);
    af[2] = (short)f2bf(a0.z);
    af[3] = (short)f2bf(a0.w);
    af[4] = (short)f2bf(a1.x);
    af[5] = (short)f2bf(a1.y);
    af[6] = (short)f2bf(a1.z);
    af[7] = (short)f2bf(a1.w);
#pragma unroll
    for (int nt = 0; nt < 8; ++nt) {
      int j = nt * 16 + l15;
      int kk = (k0 + kq * 8) ^ ((j & 7) << 3);
      short8v bf = *(const short8v*)&wl[j * 128 + kk];
      acc[nt] =
          __builtin_amdgcn_mfma_f32_16x16x32_bf16(af, bf, acc[nt], 0, 0, 0);
    }
  }
  __syncthreads();  // Wt reads done; reuse LDS for D tile [64][128] f32
#pragma unroll
  for (int nt = 0; nt < 8; ++nt) {
#pragma unroll
    for (int r = 0; r < 4; ++r) {
      int rl = wv * 16 + kq * 4 + r;
      int col = nt * 16 + l15;
      lds_f[rl * 128 + col] = acc[nt][r];
    }
  }
  __syncthreads();
  for (int i = tid; i < 2048; i += 256) {
    float4 v = *(const float4*)&lds_f[i * 4];
    int flat = i * 4;
    int r = flat >> 7;
    int cc = flat & 127;
    int gr = row0 + r;
    if (gr < M) {
      ushort4 o;
      o.x = f2bf(v.x);
      o.y = f2bf(v.y);
      o.z = f2bf(v.z);
      o.w = f2bf(v.w);
      *(ushort4*)&Y[(long)gr * H_DIM + cc] = o;
    }
  }
}

// ===========================================================================
// Gather: segment-sum transformed bf16 rows + bias + ReLU + residual.
// No LDS. 32 lanes per row, 4 cols/lane (uint2 = 4 bf16 per edge-load).
// ===========================================================================
__device__ __forceinline__ void gacc(const ushort* __restrict__ Y,
                                     const int* __restrict__ es, int e0, int e1,
                                     int c, float& a0, float& a1, float& a2,
                                     float& a3) {
  int e = e0;
  for (; e + 3 < e1; e += 4) {
    int s0 = es[e], s1 = es[e + 1], s2 = es[e + 2], s3 = es[e + 3];
    uint2 v0 = *(const uint2*)(Y + (long)s0 * H_DIM + c * 4);
    uint2 v1 = *(const uint2*)(Y + (long)s1 * H_DIM + c * 4);
    uint2 v2 = *(const uint2*)(Y + (long)s2 * H_DIM + c * 4);
    uint2 v3 = *(const uint2*)(Y + (long)s3 * H_DIM + c * 4);
    a0 += (bflo(v0.x) + bflo(v1.x)) + (bflo(v2.x) + bflo(v3.x));
    a1 += (bfhi(v0.x) + bfhi(v1.x)) + (bfhi(v2.x) + bfhi(v3.x));
    a2 += (bflo(v0.y) + bflo(v1.y)) + (bflo(v2.y) + bflo(v3.y));
    a3 += (bfhi(v0.y) + bfhi(v1.y)) + (bfhi(v2.y) + bfhi(v3.y));
  }
  for (; e < e1; ++e) {
    int s0 = es[e];
    uint2 v0 = *(const uint2*)(Y + (long)s0 * H_DIM + c * 4);
    a0 += bflo(v0.x);
    a1 += bfhi(v0.x);
    a2 += bflo(v0.y);
    a3 += bfhi(v0.y);
  }
}

__global__ __launch_bounds__(256) void gather_k(
    const ushort* __restrict__ Y1, const ushort* __restrict__ Y2,
    const ushort* __restrict__ Yp, const int* __restrict__ ro,
    const int* __restrict__ es, const float* __restrict__ rf,
    const float* __restrict__ pf, const float* __restrict__ b_r,
    const float* __restrict__ b_p, float* __restrict__ out_r,
    float* __restrict__ out_p, int nrb, int NRn, int NPn) {
  int tid = threadIdx.x;
  int lane = tid & 63;
  int wv = tid >> 6;
  int sub = lane >> 5;
  int c = lane & 31;
  int bid = blockIdx.x;

  if (bid < nrb) {
    int row0 = bid * 16;
#pragma unroll
    for (int p = 0; p < 2; ++p) {
      int row = row0 + wv * 4 + p * 2 + sub;
      if (row >= NRn) continue;
      float a0 = 0.f, a1 = 0.f, a2 = 0.f, a3 = 0.f;
      gacc(Y1, es, ro[row], ro[row + 1], c, a0, a1, a2, a3);
      gacc(Y2, es, ro[NRn + row], ro[NRn + row + 1], c, a0, a1, a2, a3);
      float4 bb = *(const float4*)&b_r[c * 4];
      a0 += bb.x;
      a1 += bb.y;
      a2 += bb.z;
      a3 += bb.w;
      a0 = a0 > 0.f ? a0 : 0.f;
      a1 = a1 > 0.f ? a1 : 0.f;
      a2 = a2 > 0.f ? a2 : 0.f;
      a3 = a3 > 0.f ? a3 : 0.f;
      float4 rv = *(const float4*)&rf[(long)row * H_DIM + c * 4];
      float4 o = {rv.x + a0, rv.y + a1, rv.z + a2, rv.w + a3};
      *(float4*)&out_r[(long)row * H_DIM + c * 4] = o;
    }
  } else {
    int row0 = (bid - nrb) * 16;
#pragma unroll
    for (int p = 0; p < 2; ++p) {
      int row = row0 + wv * 4 + p * 2 + sub;
      if (row >= NPn) continue;
      float a0 = 0.f, a1 = 0.f, a2 = 0.f, a3 = 0.f;
      int e0 = ro[2 * NRn + row], e1 = ro[2 * NRn + row + 1];
      gacc(Yp, es, e0, e1, c, a0, a1, a2, a3);
      int deg = e1 - e0;
      float inv = 1.0f / (float)(deg > 1 ? deg : 1);
      float4 bb = *(const float4*)&b_p[c * 4];
      a0 = a0 * inv + bb.x;
      a1 = a1 * inv + bb.y;
      a2 = a2 * inv + bb.z;
      a3 = a3 * inv + bb.w;
      a0 = a0 > 0.f ? a0 : 0.f;
      a1 = a1 > 0.f ? a1 : 0.f;
      a2 = a2 > 0.f ? a2 : 0.f;
      a3 = a3 > 0.f ? a3 : 0.f;
      float4 pv = *(const float4*)&pf[(long)row * H_DIM + c * 4];
      float4 o = {pv.x + a0, pv.y + a1, pv.z + a2, pv.w + a3};
      *(float4*)&out_p[(long)row * H_DIM + c * 4] = o;
    }
  }
}

extern "C" void kernel_launch(void* const* d_in, const int* in_sizes, int n_in,
                              void* d_out, int out_size, void* d_ws,
                              size_t ws_size, hipStream_t stream) {
  const float* router_feat = (const float*)d_in[0];
  const float* packet_feat = (const float*)d_in[1];
  const float* W_r = (const float*)d_in[2];
  const float* b_r = (const float*)d_in[3];
  const float* W_p = (const float*)d_in[4];
  const float* b_p = (const float*)d_in[5];
  const int* pass_src = (const int*)d_in[6];
  const int* pass_dst = (const int*)d_in[7];
  const int* connect_src = (const int*)d_in[8];
  const int* connect_dst = (const int*)d_in[9];
  const int* transfer_src = (const int*)d_in[10];
  const int* transfer_dst = (const int*)d_in[11];

  const int NRn = in_sizes[0] / H_DIM;  // 100000
  const int NPn = in_sizes[1] / H_DIM;  // 200000
  const int E0 = in_sizes[6], E1 = in_sizes[8], E2 = in_sizes[10];
  const long Etot = (long)E0 + E1 + E2;
  const int nseg = 2 * NRn + NPn;

  float* out_r = (float*)d_out;
  float* out_p = out_r + (size_t)NRn * H_DIM;

  // workspace: [ro nseg+1][cur nseg][es Etot][bsums 256] | Y1 Y2 Yp Wt (bf16)
  int* ro = (int*)d_ws;
  int* cur = ro + (nseg + 1);
  int* es = cur + nseg;
  int* bsums = es + Etot;
  size_t int_count = (size_t)(nseg + 1) + nseg + Etot + 256;
  size_t byte_off = ((int_count * 4) + 15) & ~(size_t)15;
  ushort* Y1 = (ushort*)((char*)d_ws + byte_off);
  ushort* Y2 = Y1 + (size_t)NRn * H_DIM;
  ushort* Yp = Y2 + (size_t)NPn * H_DIM;
  ushort* Wt = Yp + (size_t)NRn * H_DIM;  // 3*16384

  hipMemsetAsync(ro, 0, (size_t)(nseg + 1) * sizeof(int), stream);

  hist_all_k<<<(int)((Etot + 255) / 256), 256, 0, stream>>>(
      pass_dst, connect_dst, transfer_dst, ro, E0, E1, E2, NRn);
  int nb = (nseg + 2047) / 2048;
  scan1_k<<<nb, 256, 0, stream>>>(ro, nseg, bsums);
  scan2_k<<<1, 256, 0, stream>>>(bsums, nb);
  scan3_k<<<(nseg + 255) / 256, 256, 0, stream>>>(ro, nseg, bsums, cur,
                                                  (int)Etot);
  permute_all_k<<<(int)((Etot + 255) / 256), 256, 0, stream>>>(
      pass_src, pass_dst, connect_src, connect_dst, transfer_src, transfer_dst,
      cur, es, E0, E1, E2, NRn);

  castw_k<<<(3 * 128 * 128 + 255) / 256, 256, 0, stream>>>(W_r, W_p, Wt);

  int nb1 = (NRn + 63) / 64, nb2 = (NPn + 63) / 64, nb3 = nb1;
  gemm_k<<<nb1 + nb2 + nb3, 256, 0, stream>>>(router_feat, packet_feat, Wt, Y1,
                                              Y2, Yp, nb1, nb2, NRn, NPn);

  int nrb = (NRn + 15) / 16, npb = (NPn + 15) / 16;
  gather_k<<<nrb + npb, 256, 0, stream>>>(Y1, Y2, Yp, ro, es, router_feat,
                                          packet_feat, b_r, b_p, out_r, out_p,
                                          nrb, NRn, NPn);
}

// Round 6
// 358.063 us; speedup vs baseline: 9.5453x; 1.2291x over previous
//
#include <hip/hip_runtime.h>

#define H_DIM 128

typedef __attribute__((ext_vector_type(8))) short short8v;
typedef __attribute__((ext_vector_type(4))) float f32x4;

__device__ __forceinline__ ushort f2bf(float f) {
  unsigned u = __builtin_bit_cast(unsigned, f);
  u += 0x7fffu + ((u >> 16) & 1u);  // RNE
  return (ushort)(u >> 16);
}
__device__ __forceinline__ float bflo(unsigned u) {
  return __builtin_bit_cast(float, u << 16);
}
__device__ __forceinline__ float bfhi(unsigned u) {
  return __builtin_bit_cast(float, u & 0xffff0000u);
}

// ===========================================================================
// Fused: weight cast/transpose (blocks 0..191) + concatenated histogram.
// ro = [pass(NR) | connect(NR) | transfer(NP)], Wt[m][j][k] = W[k][j].
// ===========================================================================
__global__ __launch_bounds__(256) void histcast_k(
    const float* __restrict__ W_r, const float* __restrict__ W_p,
    ushort* __restrict__ Wt, const int* __restrict__ d0,
    const int* __restrict__ d1, const int* __restrict__ d2,
    int* __restrict__ ro, int n0, int n1, int n2, int NRn) {
  int bid = blockIdx.x;
  if (bid < 192) {
    int i = bid * 256 + threadIdx.x;
    int m = i >> 14;
    int j = (i >> 7) & 127;
    int k = i & 127;
    float v = (m == 0)   ? W_r[k * 128 + j]
              : (m == 1) ? W_r[(128 + k) * 128 + j]
                         : W_p[k * 128 + j];
    Wt[i] = f2bf(v);
  } else {
    int e = (bid - 192) * 256 + threadIdx.x;
    if (e < n0)
      atomicAdd(&ro[d0[e]], 1);
    else if (e < n0 + n1)
      atomicAdd(&ro[NRn + d1[e - n0]], 1);
    else if (e < n0 + n1 + n2)
      atomicAdd(&ro[2 * NRn + d2[e - n0 - n1]], 1);
  }
}

__global__ __launch_bounds__(256) void scan1_k(int* __restrict__ a, int n,
                                               int* __restrict__ bsums) {
  __shared__ int ts[256];
  int t = threadIdx.x;
  int base = blockIdx.x * 2048 + t * 8;
  int v[8];
  int s = 0;
#pragma unroll
  for (int k = 0; k < 8; ++k) {
    v[k] = (base + k < n) ? a[base + k] : 0;
    s += v[k];
  }
  ts[t] = s;
  __syncthreads();
  for (int off = 1; off < 256; off <<= 1) {
    int x = (t >= off) ? ts[t - off] : 0;
    __syncthreads();
    ts[t] += x;
    __syncthreads();
  }
  if (t == 0) bsums[blockIdx.x] = ts[255];
  int run = (t == 0) ? 0 : ts[t - 1];
#pragma unroll
  for (int k = 0; k < 8; ++k) {
    int x = v[k];
    if (base + k < n) a[base + k] = run;
    run += x;
  }
}

__global__ __launch_bounds__(256) void scan2_k(int* __restrict__ bsums,
                                               int nb) {
  __shared__ int ts[256];
  int t = threadIdx.x;
  int v = (t < nb) ? bsums[t] : 0;
  ts[t] = v;
  __syncthreads();
  for (int off = 1; off < 256; off <<= 1) {
    int x = (t >= off) ? ts[t - off] : 0;
    __syncthreads();
    ts[t] += x;
    __syncthreads();
  }
  int excl = (t == 0) ? 0 : ts[t - 1];
  if (t < nb) bsums[t] = excl;
}

__global__ __launch_bounds__(256) void scan3_k(int* __restrict__ a, int n,
                                               const int* __restrict__ bsums,
                                               int total) {
  int i = blockIdx.x * blockDim.x + threadIdx.x;
  if (i < n) a[i] += bsums[i / 2048];
  if (i == 0) a[n] = total;
}

// ===========================================================================
// Fused: dense GEMM Y(bf16) = X(f32) @ W via MFMA (even interleave slots)
// + edge permute (odd slots). Independent work co-scheduled so the
// permute's random-scatter latency hides under MFMA/LDS work.
// ===========================================================================
__global__ __launch_bounds__(256) void permgemm_k(
    const float* __restrict__ rf, const float* __restrict__ pf,
    const ushort* __restrict__ Wt, ushort* __restrict__ Y1,
    ushort* __restrict__ Y2, ushort* __restrict__ Yp,
    const int* __restrict__ s0a, const int* __restrict__ d0a,
    const int* __restrict__ s1a, const int* __restrict__ d1a,
    const int* __restrict__ s2a, const int* __restrict__ d2a,
    const int* __restrict__ ro, int* __restrict__ cnt2, int* __restrict__ es,
    int nb1, int nb2, int M1, int M2, int n0, int n1, int n2, int NRn, int ng,
    int np) {
  __shared__ float lds_f[8192];  // 32KB: Wt(bf16) during K-loop, D(f32) after
  int bid = blockIdx.x;
  int nmin = ng < np ? ng : np;
  bool do_gemm;
  int idx;
  if (bid < 2 * nmin) {
    do_gemm = !(bid & 1);
    idx = bid >> 1;
  } else {
    idx = nmin + (bid - 2 * nmin);
    do_gemm = ng > np;
  }

  if (!do_gemm) {
    long e = (long)idx * 256 + threadIdx.x;
    int src, slot;
    if (e < n0) {
      slot = d0a[e];
      src = s0a[e];
    } else if (e < n0 + n1) {
      long i = e - n0;
      slot = NRn + d1a[i];
      src = s1a[i];
    } else if (e < n0 + n1 + n2) {
      long i = e - n0 - n1;
      slot = 2 * NRn + d2a[i];
      src = s2a[i];
    } else
      return;
    int p = ro[slot] + atomicAdd(&cnt2[slot], 1);
    es[p] = src;
    return;
  }

  ushort* wl = (ushort*)lds_f;
  const float* X;
  ushort* Y;
  const ushort* Wg;
  int M, row0;
  if (idx < nb1) {
    X = rf; Y = Y1; Wg = Wt; M = M1; row0 = idx * 64;
  } else if (idx < nb1 + nb2) {
    X = pf; Y = Y2; Wg = Wt + 16384; M = M2; row0 = (idx - nb1) * 64;
  } else {
    X = rf; Y = Yp; Wg = Wt + 32768; M = M1; row0 = (idx - nb1 - nb2) * 64;
  }

  int tid = threadIdx.x;
  {  // stage Wt -> LDS, XOR swizzle on 8-ushort granularity
    const uint4* src = (const uint4*)Wg;
    for (int i = tid; i < 2048; i += 256) {
      int j = i >> 4;
      int k8 = (i & 15) * 8;
      int kk = k8 ^ ((j & 7) << 3);
      *(uint4*)&wl[j * 128 + kk] = src[i];
    }
  }
  __syncthreads();

  int lane = tid & 63;
  int wv = tid >> 6;
  int l15 = lane & 15;
  int kq = lane >> 4;
  int rowl = wv * 16 + l15;
  int grow = row0 + rowl;
  int growc = grow < M ? grow : M - 1;

  f32x4 acc[8];
#pragma unroll
  for (int t = 0; t < 8; ++t) {
    f32x4 z = {0.f, 0.f, 0.f, 0.f};
    acc[t] = z;
  }

#pragma unroll
  for (int ks = 0; ks < 4; ++ks) {
    int k0 = ks * 32;
    const float* ap = X + (long)growc * H_DIM + k0 + kq * 8;
    float4 a0 = *(const float4*)ap;
    float4 a1 = *(const float4*)(ap + 4);
    short8v af;
    af[0] = (short)f2bf(a0.x);
    af[1] = (short)f2bf(a0.y);
    af[2] = (short)f2bf(a0.z);
    af[3] = (short)f2bf(a0.w);
    af[4] = (short)f2bf(a1.x);
    af[5] = (short)f2bf(a1.y);
    af[6] = (short)f2bf(a1.z);
    af[7] = (short)f2bf(a1.w);
#pragma unroll
    for (int nt = 0; nt < 8; ++nt) {
      int j = nt * 16 + l15;
      int kk = (k0 + kq * 8) ^ ((j & 7) << 3);
      short8v bf = *(const short8v*)&wl[j * 128 + kk];
      acc[nt] =
          __builtin_amdgcn_mfma_f32_16x16x32_bf16(af, bf, acc[nt], 0, 0, 0);
    }
  }
  __syncthreads();  // reuse LDS for D tile [64][128] f32
#pragma unroll
  for (int nt = 0; nt < 8; ++nt) {
#pragma unroll
    for (int r = 0; r < 4; ++r) {
      int rl = wv * 16 + kq * 4 + r;
      int col = nt * 16 + l15;
      lds_f[rl * 128 + col] = acc[nt][r];
    }
  }
  __syncthreads();
  for (int i = tid; i < 2048; i += 256) {
    float4 v = *(const float4*)&lds_f[i * 4];
    int flat = i * 4;
    int r = flat >> 7;
    int cc = flat & 127;
    int gr = row0 + r;
    if (gr < M) {
      ushort4 o;
      o.x = f2bf(v.x);
      o.y = f2bf(v.y);
      o.z = f2bf(v.z);
      o.w = f2bf(v.w);
      *(ushort4*)&Y[(long)gr * H_DIM + cc] = o;
    }
  }
}

// ===========================================================================
// Gather: 16 lanes/row, uint4 (8 bf16)/lane -> 4 rows per wave-instruction,
// 4-edge unroll => 16 edge-rows in flight per wave. Residual loads and out
// stores are nontemporal (via clang ext_vector f32x4) to preserve Y
// residency in L2/L3.
// ===========================================================================
__device__ __forceinline__ void gacc16(const ushort* __restrict__ Y,
                                       const int* __restrict__ es, int e0,
                                       int e1, int c8, float* a) {
  int e = e0;
  for (; e + 3 < e1; e += 4) {
    uint4 v0 = *(const uint4*)(Y + (long)es[e] * H_DIM + c8);
    uint4 v1 = *(const uint4*)(Y + (long)es[e + 1] * H_DIM + c8);
    uint4 v2 = *(const uint4*)(Y + (long)es[e + 2] * H_DIM + c8);
    uint4 v3 = *(const uint4*)(Y + (long)es[e + 3] * H_DIM + c8);
    a[0] += (bflo(v0.x) + bflo(v1.x)) + (bflo(v2.x) + bflo(v3.x));
    a[1] += (bfhi(v0.x) + bfhi(v1.x)) + (bfhi(v2.x) + bfhi(v3.x));
    a[2] += (bflo(v0.y) + bflo(v1.y)) + (bflo(v2.y) + bflo(v3.y));
    a[3] += (bfhi(v0.y) + bfhi(v1.y)) + (bfhi(v2.y) + bfhi(v3.y));
    a[4] += (bflo(v0.z) + bflo(v1.z)) + (bflo(v2.z) + bflo(v3.z));
    a[5] += (bfhi(v0.z) + bfhi(v1.z)) + (bfhi(v2.z) + bfhi(v3.z));
    a[6] += (bflo(v0.w) + bflo(v1.w)) + (bflo(v2.w) + bflo(v3.w));
    a[7] += (bfhi(v0.w) + bfhi(v1.w)) + (bfhi(v2.w) + bfhi(v3.w));
  }
  for (; e < e1; ++e) {
    uint4 v = *(const uint4*)(Y + (long)es[e] * H_DIM + c8);
    a[0] += bflo(v.x);
    a[1] += bfhi(v.x);
    a[2] += bflo(v.y);
    a[3] += bfhi(v.y);
    a[4] += bflo(v.z);
    a[5] += bfhi(v.z);
    a[6] += bflo(v.w);
    a[7] += bfhi(v.w);
  }
}

__global__ __launch_bounds__(256) void gather_k(
    const ushort* __restrict__ Y1, const ushort* __restrict__ Y2,
    const ushort* __restrict__ Yp, const int* __restrict__ ro,
    const int* __restrict__ es, const float* __restrict__ rf,
    const float* __restrict__ pf, const float* __restrict__ b_r,
    const float* __restrict__ b_p, float* __restrict__ out_r,
    float* __restrict__ out_p, int nrb, int NRn, int NPn) {
  int tid = threadIdx.x;
  int lane = tid & 63;
  int wv = tid >> 6;
  int sub = lane >> 4;       // 0..3: subrow within wave
  int c8 = (lane & 15) * 8;  // col offset (8 floats)
  int bid = blockIdx.x;

  float a[8] = {0.f, 0.f, 0.f, 0.f, 0.f, 0.f, 0.f, 0.f};
  if (bid < nrb) {
    int row = bid * 16 + wv * 4 + sub;
    if (row >= NRn) return;
    gacc16(Y1, es, ro[row], ro[row + 1], c8, a);
    gacc16(Y2, es, ro[NRn + row], ro[NRn + row + 1], c8, a);
    float4 bb0 = *(const float4*)&b_r[c8];
    float4 bb1 = *(const float4*)&b_r[c8 + 4];
    float bv[8] = {bb0.x, bb0.y, bb0.z, bb0.w, bb1.x, bb1.y, bb1.z, bb1.w};
    const f32x4* rp = (const f32x4*)&rf[(long)row * H_DIM + c8];
    f32x4 rv0 = __builtin_nontemporal_load(rp);
    f32x4 rv1 = __builtin_nontemporal_load(rp + 1);
    f32x4 o0, o1;
#pragma unroll
    for (int i = 0; i < 4; ++i) {
      float v = a[i] + bv[i];
      v = v > 0.f ? v : 0.f;
      o0[i] = rv0[i] + v;
      float v2 = a[i + 4] + bv[i + 4];
      v2 = v2 > 0.f ? v2 : 0.f;
      o1[i] = rv1[i] + v2;
    }
    f32x4* op = (f32x4*)&out_r[(long)row * H_DIM + c8];
    __builtin_nontemporal_store(o0, op);
    __builtin_nontemporal_store(o1, op + 1);
  } else {
    int row = (bid - nrb) * 16 + wv * 4 + sub;
    if (row >= NPn) return;
    int e0 = ro[2 * NRn + row], e1 = ro[2 * NRn + row + 1];
    gacc16(Yp, es, e0, e1, c8, a);
    int deg = e1 - e0;
    float inv = 1.0f / (float)(deg > 1 ? deg : 1);
    float4 bb0 = *(const float4*)&b_p[c8];
    float4 bb1 = *(const float4*)&b_p[c8 + 4];
    float bv[8] = {bb0.x, bb0.y, bb0.z, bb0.w, bb1.x, bb1.y, bb1.z, bb1.w};
    const f32x4* pp = (const f32x4*)&pf[(long)row * H_DIM + c8];
    f32x4 pv0 = __builtin_nontemporal_load(pp);
    f32x4 pv1 = __builtin_nontemporal_load(pp + 1);
    f32x4 o0, o1;
#pragma unroll
    for (int i = 0; i < 4; ++i) {
      float v = a[i] * inv + bv[i];
      v = v > 0.f ? v : 0.f;
      o0[i] = pv0[i] + v;
      float v2 = a[i + 4] * inv + bv[i + 4];
      v2 = v2 > 0.f ? v2 : 0.f;
      o1[i] = pv1[i] + v2;
    }
    f32x4* op = (f32x4*)&out_p[(long)row * H_DIM + c8];
    __builtin_nontemporal_store(o0, op);
    __builtin_nontemporal_store(o1, op + 1);
  }
}

extern "C" void kernel_launch(void* const* d_in, const int* in_sizes, int n_in,
                              void* d_out, int out_size, void* d_ws,
                              size_t ws_size, hipStream_t stream) {
  const float* router_feat = (const float*)d_in[0];
  const float* packet_feat = (const float*)d_in[1];
  const float* W_r = (const float*)d_in[2];
  const float* b_r = (const float*)d_in[3];
  const float* W_p = (const float*)d_in[4];
  const float* b_p = (const float*)d_in[5];
  const int* pass_src = (const int*)d_in[6];
  const int* pass_dst = (const int*)d_in[7];
  const int* connect_src = (const int*)d_in[8];
  const int* connect_dst = (const int*)d_in[9];
  const int* transfer_src = (const int*)d_in[10];
  const int* transfer_dst = (const int*)d_in[11];

  const int NRn = in_sizes[0] / H_DIM;  // 100000
  const int NPn = in_sizes[1] / H_DIM;  // 200000
  const int E0 = in_sizes[6], E1 = in_sizes[8], E2 = in_sizes[10];
  const long Etot = (long)E0 + E1 + E2;
  const int nseg = 2 * NRn + NPn;

  float* out_r = (float*)d_out;
  float* out_p = out_r + (size_t)NRn * H_DIM;

  // workspace: [ro nseg+1][cnt2 nseg][es Etot][bsums 256] | Y1 Y2 Yp Wt
  int* ro = (int*)d_ws;
  int* cnt2 = ro + (nseg + 1);
  int* es = cnt2 + nseg;
  int* bsums = es + Etot;
  size_t int_count = (size_t)(nseg + 1) + nseg + Etot + 256;
  size_t byte_off = ((int_count * 4) + 15) & ~(size_t)15;
  ushort* Y1 = (ushort*)((char*)d_ws + byte_off);
  ushort* Y2 = Y1 + (size_t)NRn * H_DIM;
  ushort* Yp = Y2 + (size_t)NPn * H_DIM;
  ushort* Wt = Yp + (size_t)NRn * H_DIM;  // 3*16384

  (void)hipMemsetAsync(ro, 0, (size_t)(2 * nseg + 1) * sizeof(int), stream);

  int egrid = (int)((Etot + 255) / 256);
  histcast_k<<<192 + egrid, 256, 0, stream>>>(W_r, W_p, Wt, pass_dst,
                                              connect_dst, transfer_dst, ro, E0,
                                              E1, E2, NRn);
  int nb = (nseg + 2047) / 2048;
  scan1_k<<<nb, 256, 0, stream>>>(ro, nseg, bsums);
  scan2_k<<<1, 256, 0, stream>>>(bsums, nb);
  scan3_k<<<(nseg + 255) / 256, 256, 0, stream>>>(ro, nseg, bsums, (int)Etot);

  int nb1 = (NRn + 63) / 64, nb2 = (NPn + 63) / 64, nb3 = nb1;
  int ng = nb1 + nb2 + nb3;
  int np = egrid;
  permgemm_k<<<ng + np, 256, 0, stream>>>(
      router_feat, packet_feat, Wt, Y1, Y2, Yp, pass_src, pass_dst, connect_src,
      connect_dst, transfer_src, transfer_dst, ro, cnt2, es, nb1, nb2, NRn, NPn,
      E0, E1, E2, NRn, ng, np);

  int nrb = (NRn + 15) / 16, npb = (NPn + 15) / 16;
  gather_k<<<nrb + npb, 256, 0, stream>>>(Y1, Y2, Yp, ro, es, router_feat,
                                          packet_feat, b_r, b_p, out_r, out_p,
                                          nrb, NRn, NPn);
}

// Round 7
// 321.004 us; speedup vs baseline: 10.6473x; 1.1154x over previous
//
#include <hip/hip_runtime.h>

#define H_DIM 128

typedef __attribute__((ext_vector_type(8))) short short8v;
typedef __attribute__((ext_vector_type(4))) float f32x4;

__device__ __forceinline__ ushort f2bf(float f) {
  unsigned u = __builtin_bit_cast(unsigned, f);
  u += 0x7fffu + ((u >> 16) & 1u);  // RNE
  return (ushort)(u >> 16);
}
__device__ __forceinline__ float bflo(unsigned u) {
  return __builtin_bit_cast(float, u << 16);
}
__device__ __forceinline__ float bfhi(unsigned u) {
  return __builtin_bit_cast(float, u & 0xffff0000u);
}

// ===========================================================================
// Fused: weight cast/transpose (blocks 0..191) + concatenated histogram.
// The histogram atomic's RETURN VALUE is the edge's within-segment rank --
// stored to rank[e] so the later permute needs no atomics at all.
// ===========================================================================
__global__ __launch_bounds__(256) void histcast_k(
    const float* __restrict__ W_r, const float* __restrict__ W_p,
    ushort* __restrict__ Wt, const int* __restrict__ d0,
    const int* __restrict__ d1, const int* __restrict__ d2,
    int* __restrict__ ro, int* __restrict__ rank, int n0, int n1, int n2,
    int NRn) {
  int bid = blockIdx.x;
  if (bid < 192) {
    int i = bid * 256 + threadIdx.x;
    int m = i >> 14;
    int j = (i >> 7) & 127;
    int k = i & 127;
    float v = (m == 0)   ? W_r[k * 128 + j]
              : (m == 1) ? W_r[(128 + k) * 128 + j]
                         : W_p[k * 128 + j];
    Wt[i] = f2bf(v);
  } else {
    int e = (bid - 192) * 256 + threadIdx.x;
    int slot;
    if (e < n0)
      slot = d0[e];
    else if (e < n0 + n1)
      slot = NRn + d1[e - n0];
    else if (e < n0 + n1 + n2)
      slot = 2 * NRn + d2[e - n0 - n1];
    else
      return;
    rank[e] = atomicAdd(&ro[slot], 1);
  }
}

// Per-block (2048 elems) exclusive scan in-place; block sums -> bsums.
__global__ __launch_bounds__(256) void scan1_k(int* __restrict__ a, int n,
                                               int* __restrict__ bsums) {
  __shared__ int ts[256];
  int t = threadIdx.x;
  int base = blockIdx.x * 2048 + t * 8;
  int v[8];
  int s = 0;
#pragma unroll
  for (int k = 0; k < 8; ++k) {
    v[k] = (base + k < n) ? a[base + k] : 0;
    s += v[k];
  }
  ts[t] = s;
  __syncthreads();
  for (int off = 1; off < 256; off <<= 1) {
    int x = (t >= off) ? ts[t - off] : 0;
    __syncthreads();
    ts[t] += x;
    __syncthreads();
  }
  if (t == 0) bsums[blockIdx.x] = ts[255];
  int run = (t == 0) ? 0 : ts[t - 1];
#pragma unroll
  for (int k = 0; k < 8; ++k) {
    int x = v[k];
    if (base + k < n) a[base + k] = run;
    run += x;
  }
}

// Merged scan2+scan3: every block redundantly scans bsums (nb<=256) in LDS,
// then adds its block's exclusive offset to its 2048 elements.
__global__ __launch_bounds__(256) void scan23_k(int* __restrict__ a, int n,
                                                const int* __restrict__ bsums,
                                                int nb, int total) {
  __shared__ int ts[256];
  int t = threadIdx.x;
  int v = (t < nb) ? bsums[t] : 0;
  ts[t] = v;
  __syncthreads();
  for (int off = 1; off < 256; off <<= 1) {
    int x = (t >= off) ? ts[t - off] : 0;
    __syncthreads();
    ts[t] += x;
    __syncthreads();
  }
  int b = blockIdx.x;
  int excl = (b == 0) ? 0 : ts[b - 1];
  int base = b * 2048;
#pragma unroll
  for (int k = 0; k < 8; ++k) {
    int i = base + k * 256 + t;
    if (i < n) a[i] += excl;
  }
  if (b == 0 && t == 0) a[n] = total;
}

// ===========================================================================
// Fused: dense GEMM Y(bf16) = X(f32) @ W via MFMA + atomic-free edge permute,
// proportionally interleaved so scatter latency hides under MFMA/LDS work.
// ===========================================================================
__global__ __launch_bounds__(256) void permgemm_k(
    const float* __restrict__ rf, const float* __restrict__ pf,
    const ushort* __restrict__ Wt, ushort* __restrict__ Y1,
    ushort* __restrict__ Y2, ushort* __restrict__ Yp,
    const int* __restrict__ s0a, const int* __restrict__ d0a,
    const int* __restrict__ s1a, const int* __restrict__ d1a,
    const int* __restrict__ s2a, const int* __restrict__ d2a,
    const int* __restrict__ ro, const int* __restrict__ rank,
    int* __restrict__ es, int nb1, int nb2, int M1, int M2, int n0, int n1,
    int n2, int NRn, int ng, int np) {
  __shared__ float lds_f[8192];  // 32KB: Wt(bf16) during K-loop, D(f32) after
  long T = (long)ng + np;
  long b = blockIdx.x;
  int g_before = (int)((b * ng) / T);
  int g_incl = (int)(((b + 1) * ng) / T);
  bool do_gemm = g_incl > g_before;
  int idx = do_gemm ? g_before : (int)(b - g_before);

  if (!do_gemm) {
    long e = (long)idx * 256 + threadIdx.x;
    int src, slot;
    if (e < n0) {
      slot = d0a[e];
      src = s0a[e];
    } else if (e < n0 + n1) {
      long i = e - n0;
      slot = NRn + d1a[i];
      src = s1a[i];
    } else if (e < n0 + n1 + n2) {
      long i = e - n0 - n1;
      slot = 2 * NRn + d2a[i];
      src = s2a[i];
    } else
      return;
    es[ro[slot] + rank[e]] = src;
    return;
  }

  ushort* wl = (ushort*)lds_f;
  const float* X;
  ushort* Y;
  const ushort* Wg;
  int M, row0;
  if (idx < nb1) {
    X = rf; Y = Y1; Wg = Wt; M = M1; row0 = idx * 64;
  } else if (idx < nb1 + nb2) {
    X = pf; Y = Y2; Wg = Wt + 16384; M = M2; row0 = (idx - nb1) * 64;
  } else {
    X = rf; Y = Yp; Wg = Wt + 32768; M = M1; row0 = (idx - nb1 - nb2) * 64;
  }

  int tid = threadIdx.x;
  {  // stage Wt -> LDS, XOR swizzle on 8-ushort granularity
    const uint4* src = (const uint4*)Wg;
    for (int i = tid; i < 2048; i += 256) {
      int j = i >> 4;
      int k8 = (i & 15) * 8;
      int kk = k8 ^ ((j & 7) << 3);
      *(uint4*)&wl[j * 128 + kk] = src[i];
    }
  }
  __syncthreads();

  int lane = tid & 63;
  int wv = tid >> 6;
  int l15 = lane & 15;
  int kq = lane >> 4;
  int rowl = wv * 16 + l15;
  int grow = row0 + rowl;
  int growc = grow < M ? grow : M - 1;

  f32x4 acc[8];
#pragma unroll
  for (int t = 0; t < 8; ++t) {
    f32x4 z = {0.f, 0.f, 0.f, 0.f};
    acc[t] = z;
  }

#pragma unroll
  for (int ks = 0; ks < 4; ++ks) {
    int k0 = ks * 32;
    const float* ap = X + (long)growc * H_DIM + k0 + kq * 8;
    float4 a0 = *(const float4*)ap;
    float4 a1 = *(const float4*)(ap + 4);
    short8v af;
    af[0] = (short)f2bf(a0.x);
    af[1] = (short)f2bf(a0.y);
    af[2] = (short)f2bf(a0.z);
    af[3] = (short)f2bf(a0.w);
    af[4] = (short)f2bf(a1.x);
    af[5] = (short)f2bf(a1.y);
    af[6] = (short)f2bf(a1.z);
    af[7] = (short)f2bf(a1.w);
#pragma unroll
    for (int nt = 0; nt < 8; ++nt) {
      int j = nt * 16 + l15;
      int kk = (k0 + kq * 8) ^ ((j & 7) << 3);
      short8v bf = *(const short8v*)&wl[j * 128 + kk];
      acc[nt] =
          __builtin_amdgcn_mfma_f32_16x16x32_bf16(af, bf, acc[nt], 0, 0, 0);
    }
  }
  __syncthreads();  // reuse LDS for D tile [64][128] f32, kq-XOR swizzled
#pragma unroll
  for (int nt = 0; nt < 8; ++nt) {
#pragma unroll
    for (int r = 0; r < 4; ++r) {
      int rl = wv * 16 + kq * 4 + r;
      int col = (nt * 16 + l15) ^ (kq << 4);
      lds_f[rl * 128 + col] = acc[nt][r];
    }
  }
  __syncthreads();
  for (int i = tid; i < 2048; i += 256) {
    int flat = i * 4;
    int r = flat >> 7;
    int cc = flat & 127;
    int sw = ((r >> 2) & 3) << 4;
    float4 v = *(const float4*)&lds_f[r * 128 + (cc ^ sw)];
    int gr = row0 + r;
    if (gr < M) {
      ushort4 o;
      o.x = f2bf(v.x);
      o.y = f2bf(v.y);
      o.z = f2bf(v.z);
      o.w = f2bf(v.w);
      *(ushort4*)&Y[(long)gr * H_DIM + cc] = o;
    }
  }
}

// ===========================================================================
// Gather: 16 lanes/row, uint4 (8 bf16)/lane -> 4 rows per wave-instruction,
// 4-edge unroll => 16 edge-rows in flight per wave. Residual loads and out
// stores are nontemporal to preserve Y residency in L2/L3.
// ===========================================================================
__device__ __forceinline__ void gacc16(const ushort* __restrict__ Y,
                                       const int* __restrict__ es, int e0,
                                       int e1, int c8, float* a) {
  int e = e0;
  for (; e + 3 < e1; e += 4) {
    uint4 v0 = *(const uint4*)(Y + (long)es[e] * H_DIM + c8);
    uint4 v1 = *(const uint4*)(Y + (long)es[e + 1] * H_DIM + c8);
    uint4 v2 = *(const uint4*)(Y + (long)es[e + 2] * H_DIM + c8);
    uint4 v3 = *(const uint4*)(Y + (long)es[e + 3] * H_DIM + c8);
    a[0] += (bflo(v0.x) + bflo(v1.x)) + (bflo(v2.x) + bflo(v3.x));
    a[1] += (bfhi(v0.x) + bfhi(v1.x)) + (bfhi(v2.x) + bfhi(v3.x));
    a[2] += (bflo(v0.y) + bflo(v1.y)) + (bflo(v2.y) + bflo(v3.y));
    a[3] += (bfhi(v0.y) + bfhi(v1.y)) + (bfhi(v2.y) + bfhi(v3.y));
    a[4] += (bflo(v0.z) + bflo(v1.z)) + (bflo(v2.z) + bflo(v3.z));
    a[5] += (bfhi(v0.z) + bfhi(v1.z)) + (bfhi(v2.z) + bfhi(v3.z));
    a[6] += (bflo(v0.w) + bflo(v1.w)) + (bflo(v2.w) + bflo(v3.w));
    a[7] += (bfhi(v0.w) + bfhi(v1.w)) + (bfhi(v2.w) + bfhi(v3.w));
  }
  for (; e < e1; ++e) {
    uint4 v = *(const uint4*)(Y + (long)es[e] * H_DIM + c8);
    a[0] += bflo(v.x);
    a[1] += bfhi(v.x);
    a[2] += bflo(v.y);
    a[3] += bfhi(v.y);
    a[4] += bflo(v.z);
    a[5] += bfhi(v.z);
    a[6] += bflo(v.w);
    a[7] += bfhi(v.w);
  }
}

__global__ __launch_bounds__(256) void gather_k(
    const ushort* __restrict__ Y1, const ushort* __restrict__ Y2,
    const ushort* __restrict__ Yp, const int* __restrict__ ro,
    const int* __restrict__ es, const float* __restrict__ rf,
    const float* __restrict__ pf, const float* __restrict__ b_r,
    const float* __restrict__ b_p, float* __restrict__ out_r,
    float* __restrict__ out_p, int nrb, int NRn, int NPn) {
  int tid = threadIdx.x;
  int lane = tid & 63;
  int wv = tid >> 6;
  int sub = lane >> 4;       // 0..3: subrow within wave
  int c8 = (lane & 15) * 8;  // col offset (8 floats)
  int bid = blockIdx.x;

  float a[8] = {0.f, 0.f, 0.f, 0.f, 0.f, 0.f, 0.f, 0.f};
  if (bid < nrb) {
    int row = bid * 16 + wv * 4 + sub;
    if (row >= NRn) return;
    gacc16(Y1, es, ro[row], ro[row + 1], c8, a);
    gacc16(Y2, es, ro[NRn + row], ro[NRn + row + 1], c8, a);
    float4 bb0 = *(const float4*)&b_r[c8];
    float4 bb1 = *(const float4*)&b_r[c8 + 4];
    float bv[8] = {bb0.x, bb0.y, bb0.z, bb0.w, bb1.x, bb1.y, bb1.z, bb1.w};
    const f32x4* rp = (const f32x4*)&rf[(long)row * H_DIM + c8];
    f32x4 rv0 = __builtin_nontemporal_load(rp);
    f32x4 rv1 = __builtin_nontemporal_load(rp + 1);
    f32x4 o0, o1;
#pragma unroll
    for (int i = 0; i < 4; ++i) {
      float v = a[i] + bv[i];
      v = v > 0.f ? v : 0.f;
      o0[i] = rv0[i] + v;
      float v2 = a[i + 4] + bv[i + 4];
      v2 = v2 > 0.f ? v2 : 0.f;
      o1[i] = rv1[i] + v2;
    }
    f32x4* op = (f32x4*)&out_r[(long)row * H_DIM + c8];
    __builtin_nontemporal_store(o0, op);
    __builtin_nontemporal_store(o1, op + 1);
  } else {
    int row = (bid - nrb) * 16 + wv * 4 + sub;
    if (row >= NPn) return;
    int e0 = ro[2 * NRn + row], e1 = ro[2 * NRn + row + 1];
    gacc16(Yp, es, e0, e1, c8, a);
    int deg = e1 - e0;
    float inv = 1.0f / (float)(deg > 1 ? deg : 1);
    float4 bb0 = *(const float4*)&b_p[c8];
    float4 bb1 = *(const float4*)&b_p[c8 + 4];
    float bv[8] = {bb0.x, bb0.y, bb0.z, bb0.w, bb1.x, bb1.y, bb1.z, bb1.w};
    const f32x4* pp = (const f32x4*)&pf[(long)row * H_DIM + c8];
    f32x4 pv0 = __builtin_nontemporal_load(pp);
    f32x4 pv1 = __builtin_nontemporal_load(pp + 1);
    f32x4 o0, o1;
#pragma unroll
    for (int i = 0; i < 4; ++i) {
      float v = a[i] * inv + bv[i];
      v = v > 0.f ? v : 0.f;
      o0[i] = pv0[i] + v;
      float v2 = a[i + 4] * inv + bv[i + 4];
      v2 = v2 > 0.f ? v2 : 0.f;
      o1[i] = pv1[i] + v2;
    }
    f32x4* op = (f32x4*)&out_p[(long)row * H_DIM + c8];
    __builtin_nontemporal_store(o0, op);
    __builtin_nontemporal_store(o1, op + 1);
  }
}

extern "C" void kernel_launch(void* const* d_in, const int* in_sizes, int n_in,
                              void* d_out, int out_size, void* d_ws,
                              size_t ws_size, hipStream_t stream) {
  const float* router_feat = (const float*)d_in[0];
  const float* packet_feat = (const float*)d_in[1];
  const float* W_r = (const float*)d_in[2];
  const float* b_r = (const float*)d_in[3];
  const float* W_p = (const float*)d_in[4];
  const float* b_p = (const float*)d_in[5];
  const int* pass_src = (const int*)d_in[6];
  const int* pass_dst = (const int*)d_in[7];
  const int* connect_src = (const int*)d_in[8];
  const int* connect_dst = (const int*)d_in[9];
  const int* transfer_src = (const int*)d_in[10];
  const int* transfer_dst = (const int*)d_in[11];

  const int NRn = in_sizes[0] / H_DIM;  // 100000
  const int NPn = in_sizes[1] / H_DIM;  // 200000
  const int E0 = in_sizes[6], E1 = in_sizes[8], E2 = in_sizes[10];
  const long Etot = (long)E0 + E1 + E2;
  const int nseg = 2 * NRn + NPn;

  float* out_r = (float*)d_out;
  float* out_p = out_r + (size_t)NRn * H_DIM;

  // workspace: [ro nseg+1][rank Etot][es Etot][bsums 256] | Y1 Y2 Yp Wt
  int* ro = (int*)d_ws;
  int* rank = ro + (nseg + 1);
  int* es = rank + Etot;
  int* bsums = es + Etot;
  size_t int_count = (size_t)(nseg + 1) + 2 * (size_t)Etot + 256;
  size_t byte_off = ((int_count * 4) + 15) & ~(size_t)15;
  ushort* Y1 = (ushort*)((char*)d_ws + byte_off);
  ushort* Y2 = Y1 + (size_t)NRn * H_DIM;
  ushort* Yp = Y2 + (size_t)NPn * H_DIM;
  ushort* Wt = Yp + (size_t)NRn * H_DIM;  // 3*16384

  (void)hipMemsetAsync(ro, 0, (size_t)(nseg + 1) * sizeof(int), stream);

  int egrid = (int)((Etot + 255) / 256);
  histcast_k<<<192 + egrid, 256, 0, stream>>>(W_r, W_p, Wt, pass_dst,
                                              connect_dst, transfer_dst, ro,
                                              rank, E0, E1, E2, NRn);
  int nb = (nseg + 2047) / 2048;
  scan1_k<<<nb, 256, 0, stream>>>(ro, nseg, bsums);
  scan23_k<<<nb, 256, 0, stream>>>(ro, nseg, bsums, nb, (int)Etot);

  int nb1 = (NRn + 63) / 64, nb2 = (NPn + 63) / 64, nb3 = nb1;
  int ng = nb1 + nb2 + nb3;
  int np = egrid;
  permgemm_k<<<ng + np, 256, 0, stream>>>(
      router_feat, packet_feat, Wt, Y1, Y2, Yp, pass_src, pass_dst, connect_src,
      connect_dst, transfer_src, transfer_dst, ro, rank, es, nb1, nb2, NRn, NPn,
      E0, E1, E2, NRn, ng, np);

  int nrb = (NRn + 15) / 16, npb = (NPn + 15) / 16;
  gather_k<<<nrb + npb, 256, 0, stream>>>(Y1, Y2, Yp, ro, es, router_feat,
                                          packet_feat, b_r, b_p, out_r, out_p,
                                          nrb, NRn, NPn);
}